// Round 1
// baseline (378.112 us; speedup 1.0000x reference)
//
#include <hip/hip_runtime.h>
#include <hip/hip_bf16.h>

#define N_PTS 100000
#define KNN   16
#define NK    (N_PTS * KNN)
#define CIN   64
#define CMID  64
#define COUT  128

// ---------------- ws layout (bytes) ----------------
// [0, 400000)          counts (int32, N_PTS)
// [401408, 404480)     stats/coeffs: S1[64] Q1[64] A1[64] B1[64] S2[128] Q2[128] A2[128] B2[128]
// [405504, +25.6MB)    z1 (N*64 f32)  -- later aliased as h2 (N*128 bf16, same 25.6MB)
// [26005504, +51.2MB)  z2 (N*128 f32)
// total: 77,205,504 bytes
#define OFF_STATS 401408
#define OFF_Z1    405504
#define OFF_Z2    26005504

__device__ __forceinline__ unsigned short f2bf(float f) {
    unsigned u = __float_as_uint(f);
    unsigned r = (u + 0x7fffu + ((u >> 16) & 1u)) >> 16;   // round-to-nearest-even
    return (unsigned short)r;
}

// ---- 1. histogram of reference_index -> counts ----
__global__ __launch_bounds__(256) void hist_k(const int* __restrict__ idx,
                                              int* __restrict__ counts) {
    int i = blockIdx.x * 256 + threadIdx.x;
    if (i < NK) atomicAdd(&counts[idx[i]], 1);
}

// ---- 2. z1 = feat @ W1 + b1  (one row per thread, 64 fp32 accumulators) ----
__global__ __launch_bounds__(256) void gemm1_k(const float* __restrict__ feat,
                                               const float* __restrict__ W1,
                                               const float* __restrict__ b1,
                                               float* __restrict__ z1) {
    __shared__ float Wl[CIN * CMID];
    for (int i = threadIdx.x; i < CIN * CMID / 4; i += 256)
        ((float4*)Wl)[i] = ((const float4*)W1)[i];
    __syncthreads();

    int row = blockIdx.x * 256 + threadIdx.x;
    if (row >= N_PTS) return;

    float acc[CMID];
    #pragma unroll
    for (int j = 0; j < CMID; j++) acc[j] = b1[j];

    const float4* fr = (const float4*)(feat + (size_t)row * CIN);
    #pragma unroll 4
    for (int c4 = 0; c4 < CIN / 4; c4++) {
        float4 f = fr[c4];
        const float* wr = Wl + c4 * 4 * CMID;
        #pragma unroll
        for (int j = 0; j < CMID; j++) acc[j] = fmaf(f.x, wr[j], acc[j]);
        #pragma unroll
        for (int j = 0; j < CMID; j++) acc[j] = fmaf(f.y, wr[CMID + j], acc[j]);
        #pragma unroll
        for (int j = 0; j < CMID; j++) acc[j] = fmaf(f.z, wr[2 * CMID + j], acc[j]);
        #pragma unroll
        for (int j = 0; j < CMID; j++) acc[j] = fmaf(f.w, wr[3 * CMID + j], acc[j]);
    }
    float4* zr = (float4*)(z1 + (size_t)row * CMID);
    #pragma unroll
    for (int j = 0; j < CMID / 4; j++)
        zr[j] = make_float4(acc[4 * j], acc[4 * j + 1], acc[4 * j + 2], acc[4 * j + 3]);
}

// ---- 3/6. weighted channel stats: S += cnt*z, Q += cnt*z^2 ----
template <int C>
__global__ __launch_bounds__(256) void stats_k(const float* __restrict__ z,
                                               const int* __restrict__ counts,
                                               float* __restrict__ S,
                                               float* __restrict__ Q) {
    const int GP = 256 / C;                 // row-groups per block
    int c = threadIdx.x % C;
    int g = threadIdx.x / C;
    float s = 0.f, q = 0.f;
    for (int row = blockIdx.x * GP + g; row < N_PTS; row += gridDim.x * GP) {
        float cnt = (float)counts[row];
        float zv  = z[(size_t)row * C + c];
        float cz  = cnt * zv;
        s += cz;
        q = fmaf(cz, zv, q);
    }
    __shared__ float sm[256], qm[256];
    sm[threadIdx.x] = s;
    qm[threadIdx.x] = q;
    __syncthreads();
    if (threadIdx.x < C) {
        float ts = 0.f, tq = 0.f;
        #pragma unroll
        for (int i = 0; i < GP; i++) { ts += sm[threadIdx.x + i * C]; tq += qm[threadIdx.x + i * C]; }
        atomicAdd(&S[threadIdx.x], ts);
        atomicAdd(&Q[threadIdx.x], tq);
    }
}

// ---- 4/7. finalize BN coeffs: h = relu(z*A + B) ----
__global__ void fin_k(const float* __restrict__ S, const float* __restrict__ Q,
                      const float* __restrict__ gamma, const float* __restrict__ beta,
                      float* __restrict__ A, float* __restrict__ B, int C) {
    int c = threadIdx.x;
    if (c < C) {
        const float inv = 1.0f / (float)NK;
        float m = S[c] * inv;
        float v = Q[c] * inv - m * m;
        float a = gamma[c] * rsqrtf(v + 1e-5f);
        A[c] = a;
        B[c] = beta[c] - m * a;
    }
}

// ---- 5. z2 = relu(z1*A1+B1) @ W2 + b2 ; blockIdx.y selects output-channel half ----
__global__ __launch_bounds__(256) void gemm2_k(const float* __restrict__ z1,
                                               const float* __restrict__ A1,
                                               const float* __restrict__ B1,
                                               const float* __restrict__ W2,
                                               const float* __restrict__ b2,
                                               float* __restrict__ z2) {
    __shared__ float Wl[CMID * 64];
    __shared__ float Al[CMID], Bl[CMID];
    int half = blockIdx.y;
    for (int i = threadIdx.x; i < CMID * 64 / 4; i += 256) {
        int c = i >> 4, jj = i & 15;
        ((float4*)Wl)[i] = ((const float4*)W2)[c * (COUT / 4) + half * 16 + jj];
    }
    if (threadIdx.x < CMID) { Al[threadIdx.x] = A1[threadIdx.x]; Bl[threadIdx.x] = B1[threadIdx.x]; }
    __syncthreads();

    int row = blockIdx.x * 256 + threadIdx.x;
    if (row >= N_PTS) return;

    float acc[64];
    #pragma unroll
    for (int j = 0; j < 64; j++) acc[j] = b2[half * 64 + j];

    const float4* zr = (const float4*)(z1 + (size_t)row * CMID);
    #pragma unroll 2
    for (int c4 = 0; c4 < CMID / 4; c4++) {
        float4 zf = zr[c4];
        int c = c4 * 4;
        float h0 = fmaxf(fmaf(zf.x, Al[c + 0], Bl[c + 0]), 0.f);
        float h1 = fmaxf(fmaf(zf.y, Al[c + 1], Bl[c + 1]), 0.f);
        float h2 = fmaxf(fmaf(zf.z, Al[c + 2], Bl[c + 2]), 0.f);
        float h3 = fmaxf(fmaf(zf.w, Al[c + 3], Bl[c + 3]), 0.f);
        const float* wr = Wl + c * 64;
        #pragma unroll
        for (int j = 0; j < 64; j++) acc[j] = fmaf(h0, wr[j], acc[j]);
        #pragma unroll
        for (int j = 0; j < 64; j++) acc[j] = fmaf(h1, wr[64 + j], acc[j]);
        #pragma unroll
        for (int j = 0; j < 64; j++) acc[j] = fmaf(h2, wr[128 + j], acc[j]);
        #pragma unroll
        for (int j = 0; j < 64; j++) acc[j] = fmaf(h3, wr[192 + j], acc[j]);
    }
    float4* zo = (float4*)(z2 + (size_t)row * COUT + half * 64);
    #pragma unroll
    for (int j = 0; j < 16; j++)
        zo[j] = make_float4(acc[4 * j], acc[4 * j + 1], acc[4 * j + 2], acc[4 * j + 3]);
}

// ---- 8. h2 = bf16(relu(z2*A2+B2)) ----
__global__ __launch_bounds__(256) void h2_k(const float* __restrict__ z2,
                                            const float* __restrict__ A2,
                                            const float* __restrict__ B2,
                                            unsigned short* __restrict__ h2) {
    __shared__ float Al[COUT], Bl[COUT];
    if (threadIdx.x < COUT) { Al[threadIdx.x] = A2[threadIdx.x]; Bl[threadIdx.x] = B2[threadIdx.x]; }
    __syncthreads();
    int i = blockIdx.x * 256 + threadIdx.x;       // float4-group index over N*128
    if (i >= N_PTS * COUT / 4) return;
    float4 z = ((const float4*)z2)[i];
    int c = (i * 4) & (COUT - 1);
    float h0 = fmaxf(fmaf(z.x, Al[c + 0], Bl[c + 0]), 0.f);
    float h1 = fmaxf(fmaf(z.y, Al[c + 1], Bl[c + 1]), 0.f);
    float h2v = fmaxf(fmaf(z.z, Al[c + 2], Bl[c + 2]), 0.f);
    float h3 = fmaxf(fmaf(z.w, Al[c + 3], Bl[c + 3]), 0.f);
    unsigned lo = (unsigned)f2bf(h0) | ((unsigned)f2bf(h1) << 16);
    unsigned hi = (unsigned)f2bf(h2v) | ((unsigned)f2bf(h3) << 16);
    ((uint2*)h2)[i] = make_uint2(lo, hi);
}

// ---- 9. out[n,c] = max_k h2[idx[n,k],c]   (one wave per point; h2 >= 0 so init 0) ----
__global__ __launch_bounds__(256) void gather_k(const unsigned short* __restrict__ h2,
                                                const int* __restrict__ idx,
                                                float* __restrict__ out) {
    int w = threadIdx.x >> 6;
    int lane = threadIdx.x & 63;
    int n = blockIdx.x * 4 + w;
    if (n >= N_PTS) return;
    const int* ip = idx + n * KNN;
    float m0 = 0.f, m1 = 0.f;
    #pragma unroll
    for (int k = 0; k < KNN; k++) {
        int j = ip[k];
        unsigned v = ((const unsigned*)(h2 + (size_t)j * COUT))[lane];  // 2 packed bf16
        float f0 = __uint_as_float(v << 16);
        float f1 = __uint_as_float(v & 0xffff0000u);
        m0 = fmaxf(m0, f0);
        m1 = fmaxf(m1, f1);
    }
    float2 r; r.x = m0; r.y = m1;
    ((float2*)(out + (size_t)n * COUT))[lane] = r;
}

extern "C" void kernel_launch(void* const* d_in, const int* in_sizes, int n_in,
                              void* d_out, int out_size, void* d_ws, size_t ws_size,
                              hipStream_t stream) {
    const float* feat = (const float*)d_in[0];
    const int*   idx  = (const int*)d_in[1];
    const float* W1   = (const float*)d_in[2];
    const float* b1   = (const float*)d_in[3];
    const float* g1   = (const float*)d_in[4];
    const float* be1  = (const float*)d_in[5];
    const float* W2   = (const float*)d_in[6];
    const float* b2   = (const float*)d_in[7];
    const float* g2   = (const float*)d_in[8];
    const float* be2  = (const float*)d_in[9];
    float* out = (float*)d_out;

    char* ws = (char*)d_ws;
    int*   counts = (int*)ws;
    float* S1 = (float*)(ws + OFF_STATS);
    float* Q1 = S1 + 64;
    float* A1 = S1 + 128;
    float* B1 = S1 + 192;
    float* S2 = S1 + 256;
    float* Q2 = S1 + 384;
    float* A2 = S1 + 512;
    float* B2 = S1 + 640;
    float* z1 = (float*)(ws + OFF_Z1);
    unsigned short* h2 = (unsigned short*)(ws + OFF_Z1);   // alias: z1 dead before h2 written
    float* z2 = (float*)(ws + OFF_Z2);

    // zero counts + stats accumulators (region before z1)
    hipMemsetAsync(d_ws, 0, OFF_Z1, stream);

    hist_k<<<NK / 256, 256, 0, stream>>>(idx, counts);
    gemm1_k<<<(N_PTS + 255) / 256, 256, 0, stream>>>(feat, W1, b1, z1);
    stats_k<64><<<512, 256, 0, stream>>>(z1, counts, S1, Q1);
    fin_k<<<1, 128, 0, stream>>>(S1, Q1, g1, be1, A1, B1, 64);
    gemm2_k<<<dim3((N_PTS + 255) / 256, 2), 256, 0, stream>>>(z1, A1, B1, W2, b2, z2);
    stats_k<128><<<512, 256, 0, stream>>>(z2, counts, S2, Q2);
    fin_k<<<1, 128, 0, stream>>>(S2, Q2, g2, be2, A2, B2, 128);
    h2_k<<<N_PTS * COUT / 4 / 256, 256, 0, stream>>>(z2, A2, B2, h2);
    gather_k<<<N_PTS / 4, 256, 0, stream>>>(h2, idx, out);
}